// Round 2
// baseline (4190.962 us; speedup 1.0000x reference)
//
#include <hip/hip_runtime.h>
#include <hip/hip_bf16.h>

#define EDGES 600000
#define NNODES 100000
#define DIN 128
#define DHID 256
#define DOUT 128

typedef __attribute__((ext_vector_type(4))) float floatx4;
typedef __attribute__((ext_vector_type(4))) short shortx4;
typedef __attribute__((ext_vector_type(8))) short shortx8;

__device__ inline unsigned short f2bf_rne(float f) {
    union { float f; unsigned u; } v; v.f = f;
    unsigned r = v.u + 0x7FFFu + ((v.u >> 16) & 1u);
    return (unsigned short)(r >> 16);
}

// Weight swizzle: W1/W2 fp32 -> bf16 fragment-major (coalesced 1KB/wave streams).
// W1s frag (t,ks): A-frag of 16x16x32 (m=hid=t*16+col, k=ks*32+q*8+j)
// W2s frag (t,ot): B-frag of 16x16x16 (n=o=ot*16+col,  k=t*16+q*4+j)
__global__ __launch_bounds__(256) void prep_kernel(
        const float* __restrict__ W1, const float* __restrict__ W2,
        unsigned short* __restrict__ ws) {
    int j = blockIdx.x * 256 + threadIdx.x;
    if (j < 4096) {                       // W1 frags: 16t * 4ks * 64 lanes
        int lane = j & 63, fs = j >> 6;
        int ks = fs & 3, t = fs >> 2;
        int hid = t * 16 + (lane & 15), q = lane >> 4;
        const float* src = W1 + hid * DIN + ks * 32 + q * 8;
        shortx8 v;
        #pragma unroll
        for (int i = 0; i < 8; ++i) v[i] = (short)f2bf_rne(src[i]);
        *((shortx8*)ws + j) = v;
    } else if (j < 12288) {               // W2 frags: 16t * 8ot * 64 lanes
        int j2 = j - 4096;
        int lane = j2 & 63, fs = j2 >> 6;
        int ot = fs & 7, t = fs >> 3;
        int o = ot * 16 + (lane & 15), q = lane >> 4;
        const float* src = W2 + o * DHID + t * 16 + q * 4;
        shortx4 v;
        #pragma unroll
        for (int i = 0; i < 4; ++i) v[i] = (short)f2bf_rne(src[i]);
        *((shortx4*)(ws + 32768) + j2) = v;
    }
}

// x fp32 -> bf16 (halves gather bytes + TA requests in the main kernel)
__global__ __launch_bounds__(256) void prep_x_kernel(
        const float* __restrict__ x, unsigned short* __restrict__ xb) {
    int i = blockIdx.x * 256 + threadIdx.x;       // one shortx8 per thread
    const float4* s = (const float4*)x + (size_t)i * 2;
    float4 a = s[0], b = s[1];
    union { shortx8 v; __hip_bfloat162 h[4]; } p;
    p.h[0] = __float22bfloat162_rn(make_float2(a.x, a.y));
    p.h[1] = __float22bfloat162_rn(make_float2(a.z, a.w));
    p.h[2] = __float22bfloat162_rn(make_float2(b.x, b.y));
    p.h[3] = __float22bfloat162_rn(make_float2(b.z, b.w));
    ((shortx8*)xb)[i] = p.v;
}

// Fused GINConv edge-MLP, no LDS, no barriers. Each wave owns 48 edges
// (600000 = 48 * 12500 exactly -> zero tails). Gather loads exactly the
// MFMA B-fragment each lane needs: s[edge=col][k=ks*32+q*8..+7].
// GEMM1 transposed (hT = W1*sT): C-layout (col=edge,row=hid=4q+r) IS the
// A-layout of 16x16x16 GEMM2 (m=edge,k=4q+j) -> relu+bias+pack in regs.
template<bool BFX>
__global__ __launch_bounds__(256, 2) void gin_kernel(
        const float* __restrict__ x, const unsigned short* __restrict__ xb,
        const int* __restrict__ ei,
        const float* __restrict__ b1, const float* __restrict__ b2,
        const unsigned short* __restrict__ wsw,
        float* __restrict__ out) {
    const int tid = threadIdx.x, wave = tid >> 6, lane = tid & 63;
    const int q = lane >> 4, col = lane & 15;
    const int etile = blockIdx.x * 4 + wave;      // 0..12499
    const int ebase = etile * 48;

    // ---- gather: per-lane fragment-direct, registers only ----
    shortx8 sfrag[3][4];
    #pragma unroll
    for (int g = 0; g < 3; ++g) {
        const int e = ebase + g * 16 + col;
        const int na = ei[e], nb = ei[EDGES + e];
        if (BFX) {
            const shortx8* ra = (const shortx8*)xb + (size_t)na * 16 + q;
            const shortx8* rb = (const shortx8*)xb + (size_t)nb * 16 + q;
            shortx8 ua[4], ub[4];
            #pragma unroll
            for (int ks = 0; ks < 4; ++ks) { ua[ks] = ra[ks * 4]; ub[ks] = rb[ks * 4]; }
            #pragma unroll
            for (int ks = 0; ks < 4; ++ks) {
                union { shortx8 v; __hip_bfloat162 h[4]; } pa, pb, po;
                pa.v = ua[ks]; pb.v = ub[ks];
                #pragma unroll
                for (int i = 0; i < 4; ++i) {
                    float2 fa = __bfloat1622float2(pa.h[i]);
                    float2 fb = __bfloat1622float2(pb.h[i]);
                    po.h[i] = __float22bfloat162_rn(make_float2(fa.x + fb.x, fa.y + fb.y));
                }
                sfrag[g][ks] = po.v;
            }
        } else {
            const float4* ra = (const float4*)(x + (size_t)na * DIN) + q * 2;
            const float4* rb = (const float4*)(x + (size_t)nb * DIN) + q * 2;
            #pragma unroll
            for (int ks = 0; ks < 4; ++ks) {
                float4 u0 = ra[ks * 8], u1 = ra[ks * 8 + 1];
                float4 v0 = rb[ks * 8], v1 = rb[ks * 8 + 1];
                union { shortx8 v; __hip_bfloat162 h[4]; } po;
                po.h[0] = __float22bfloat162_rn(make_float2(u0.x + v0.x, u0.y + v0.y));
                po.h[1] = __float22bfloat162_rn(make_float2(u0.z + v0.z, u0.w + v0.w));
                po.h[2] = __float22bfloat162_rn(make_float2(u1.x + v1.x, u1.y + v1.y));
                po.h[3] = __float22bfloat162_rn(make_float2(u1.z + v1.z, u1.w + v1.w));
                sfrag[g][ks] = po.v;
            }
        }
    }

    float b2v[8];
    #pragma unroll
    for (int ot = 0; ot < 8; ++ot) b2v[ot] = 0.5f * b2[ot * 16 + col];

    floatx4 acc2[3][8];
    #pragma unroll
    for (int g = 0; g < 3; ++g)
        #pragma unroll
        for (int ot = 0; ot < 8; ++ot) acc2[g][ot] = (floatx4)0.0f;

    const shortx8* w1f = (const shortx8*)wsw + lane;
    const shortx4* w2f = (const shortx4*)(wsw + 32768) + lane;
    const float4* b1v4 = (const float4*)b1;

    // double-buffer the W1 A-frags across t
    shortx8 a1[2][4];
    #pragma unroll
    for (int ks = 0; ks < 4; ++ks) a1[0][ks] = w1f[ks * 64];

    #pragma unroll 1
    for (int t = 0; t < 16; ++t) {
        const int cur = t & 1, nxt = cur ^ 1;
        if (t < 15) {
            #pragma unroll
            for (int ks = 0; ks < 4; ++ks) a1[nxt][ks] = w1f[((t + 1) * 4 + ks) * 64];
        }
        shortx4 wb[8];
        #pragma unroll
        for (int ot = 0; ot < 8; ++ot) wb[ot] = w2f[(t * 8 + ot) * 64];
        const float4 bv = b1v4[t * 4 + q];
        #pragma unroll
        for (int g = 0; g < 3; ++g) {
            floatx4 acc1 = (floatx4)0.0f;
            #pragma unroll
            for (int ks = 0; ks < 4; ++ks)
                acc1 = __builtin_amdgcn_mfma_f32_16x16x32_bf16(a1[cur][ks], sfrag[g][ks], acc1, 0, 0, 0);
            union { shortx4 v; __hip_bfloat162 h[2]; } pk;
            pk.h[0] = __float22bfloat162_rn(make_float2(
                fmaxf(acc1[0] + bv.x, 0.0f), fmaxf(acc1[1] + bv.y, 0.0f)));
            pk.h[1] = __float22bfloat162_rn(make_float2(
                fmaxf(acc1[2] + bv.z, 0.0f), fmaxf(acc1[3] + bv.w, 0.0f)));
            #pragma unroll
            for (int ot = 0; ot < 8; ++ot)
                acc2[g][ot] = __builtin_amdgcn_mfma_f32_16x16x16bf16_1k(pk.v, wb[ot], acc2[g][ot], 0, 0, 0);
        }
    }

    // ---- epilogue: out = 0.5*acc2 + 0.5*b2 ; row=edge=4q+r, col=o ----
    #pragma unroll
    for (int ot = 0; ot < 8; ++ot) {
        #pragma unroll
        for (int g = 0; g < 3; ++g) {
            float* op = out + (size_t)(ebase + g * 16 + q * 4) * DOUT + ot * 16 + col;
            #pragma unroll
            for (int r = 0; r < 4; ++r)
                op[(size_t)r * DOUT] = 0.5f * acc2[g][ot][r] + b2v[ot];
        }
    }
}

extern "C" void kernel_launch(void* const* d_in, const int* in_sizes, int n_in,
                              void* d_out, int out_size, void* d_ws, size_t ws_size,
                              hipStream_t stream) {
    const float* x  = (const float*)d_in[0];
    const int*   ei = (const int*)d_in[1];
    const float* W1 = (const float*)d_in[2];
    const float* b1 = (const float*)d_in[3];
    const float* W2 = (const float*)d_in[4];
    const float* b2 = (const float*)d_in[5];
    unsigned short* ws = (unsigned short*)d_ws;

    prep_kernel<<<48, 256, 0, stream>>>(W1, W2, ws);

    unsigned short* xb = ws + 65536;                       // after 128KB weights
    const size_t need = 131072 + (size_t)NNODES * DIN * 2; // +25.6MB bf16 x
    if (ws_size >= need) {
        prep_x_kernel<<<(NNODES * DIN / 8) / 256, 256, 0, stream>>>(x, xb);
        gin_kernel<true><<<EDGES / 192, 256, 0, stream>>>(x, xb, ei, b1, b2, ws, (float*)d_out);
    } else {
        gin_kernel<false><<<EDGES / 192, 256, 0, stream>>>(x, xb, ei, b1, b2, ws, (float*)d_out);
    }
}